// Round 1
// baseline (24814.061 us; speedup 1.0000x reference)
//
#include <hip/hip_runtime.h>
#include <stddef.h>

// LSTM encoder: B=64, T=512, H=512, L=4.
// Strategy: bf16 MFMA for all matmuls (fp32 accum). Sequential layers:
//   per layer: GEMM xW = inp@W + b (fp16 out), then persistent recurrent
//   kernel (32 WGs, U slice held in VGPRs as MFMA B-frags, per-step
//   device-scope flag barrier, h broadcast via global bf16 double buffer).
// Workspace layout (assumes ws_size >= ~209 MB):
//   INP fp32 [T,B,H]           64 MB
//   XW  fp16 [T*B,4H]         128 MB
//   WBF bf16 [L][4H][H] (B^T)   8 MB
//   UBF bf16 [L][4H][H] (B^T)   8 MB
//   HBF bf16 [2][B,H]         128 KB
//   cnt int  [L][T]             8 KB

typedef float          f32x4 __attribute__((ext_vector_type(4)));
typedef short          s16x8 __attribute__((ext_vector_type(8)));
typedef unsigned short u16;
typedef u16            u16x4 __attribute__((ext_vector_type(4)));
typedef _Float16       f16x4 __attribute__((ext_vector_type(4)));

#define NWG 32

__device__ __forceinline__ u16 f2bf(float f) {
    unsigned int u = __builtin_bit_cast(unsigned int, f);
    u += 0x7FFFu + ((u >> 16) & 1u);   // round-to-nearest-even
    return (u16)(u >> 16);
}
__device__ __forceinline__ float sig(float x) { return 1.f / (1.f + __expf(-x)); }
__device__ __forceinline__ float th(float x)  { return 2.f / (1.f + __expf(-2.f * x)) - 1.f; }

__global__ void init_cnt(int* __restrict__ cnt) {
    for (int i = threadIdx.x; i < 4 * 512; i += 256) cnt[i] = 0;
}

// x[B,T,H] fp32 -> INP[T,B,H] fp32
__global__ void convert_x(const float* __restrict__ x, float* __restrict__ inp) {
#pragma unroll
    for (int i = 0; i < 8; ++i) {
        int f = blockIdx.x * 2048 + i * 256 + threadIdx.x;   // float4 index, 4.19M total
        int h4 = f & 127, b = (f >> 7) & 63, t = f >> 13;
        f32x4 v = *(const f32x4*)(x + ((size_t)b * 512 + t) * 512 + h4 * 4);
        *(f32x4*)(inp + ((size_t)t * 64 + b) * 512 + h4 * 4) = v;
    }
}

// W/U [l][k][n] fp32 -> [l][n][k] bf16 (transposed via LDS tile)
__global__ void convert_wu(const float* __restrict__ W, const float* __restrict__ U,
                           u16* __restrict__ WBF, u16* __restrict__ UBF) {
    __shared__ float tl[32][33];
    const int l = blockIdx.z & 3, which = blockIdx.z >> 2;
    const float* src = (which ? U : W) + (size_t)l * 512 * 2048;
    u16* dst = (which ? UBF : WBF) + (size_t)l * 2048 * 512;
    const int n0 = blockIdx.x * 32, k0 = blockIdx.y * 32;
    const int tid = threadIdx.x;
    const int r = tid >> 3, c4 = (tid & 7) * 4;
    f32x4 v = *(const f32x4*)(src + (size_t)(k0 + r) * 2048 + n0 + c4);
    tl[r][c4 + 0] = v[0]; tl[r][c4 + 1] = v[1]; tl[r][c4 + 2] = v[2]; tl[r][c4 + 3] = v[3];
    __syncthreads();
    u16x4 o = { f2bf(tl[c4 + 0][r]), f2bf(tl[c4 + 1][r]), f2bf(tl[c4 + 2][r]), f2bf(tl[c4 + 3][r]) };
    *(u16x4*)(dst + (size_t)(n0 + r) * 512 + k0 + c4) = o;
}

// C[M=32768,N=2048] fp16 = A[M,512] fp32 (convert) @ Bt^T (Bt = [N][K] bf16) + bias
__global__ __launch_bounds__(256) void gemm_xw(const float* __restrict__ A,
                                               const u16* __restrict__ Bt,
                                               const float* __restrict__ bias,
                                               _Float16* __restrict__ C) {
    __shared__ u16 Alds[128][72];
    __shared__ u16 Blds[128][72];
    const int tid = threadIdx.x, lane = tid & 63, wave = tid >> 6;
    const int m0 = blockIdx.y * 128, n0 = blockIdx.x * 128;
    const int wm = (wave & 1) * 64, wn = (wave >> 1) * 64;
    const int m_l = lane & 15, k_l = (lane >> 4) * 8, r0 = (lane >> 4) * 4;
    f32x4 acc[4][4] = {};
    for (int k0 = 0; k0 < 512; k0 += 64) {
        __syncthreads();
#pragma unroll
        for (int i = 0; i < 8; ++i) {                       // stage A (fp32 -> bf16)
            int f = tid + i * 256;
            int row = f >> 4, c4 = (f & 15) * 4;
            f32x4 v = *(const f32x4*)(A + (size_t)(m0 + row) * 512 + k0 + c4);
            u16x4 bv = { f2bf(v[0]), f2bf(v[1]), f2bf(v[2]), f2bf(v[3]) };
            *(u16x4*)&Alds[row][c4] = bv;
        }
#pragma unroll
        for (int i = 0; i < 4; ++i) {                       // stage B (bf16, B^T rows)
            int f = tid + i * 256;
            int row = f >> 3, c8 = (f & 7) * 8;
            *(s16x8*)&Blds[row][c8] = *(const s16x8*)(Bt + (size_t)(n0 + row) * 512 + k0 + c8);
        }
        __syncthreads();
#pragma unroll
        for (int kk = 0; kk < 2; ++kk) {
            s16x8 af[4], bfr[4];
            const int kb = kk * 32 + k_l;
#pragma unroll
            for (int mi = 0; mi < 4; ++mi) af[mi]  = *(const s16x8*)&Alds[wm + mi * 16 + m_l][kb];
#pragma unroll
            for (int ni = 0; ni < 4; ++ni) bfr[ni] = *(const s16x8*)&Blds[wn + ni * 16 + m_l][kb];
#pragma unroll
            for (int mi = 0; mi < 4; ++mi)
#pragma unroll
                for (int ni = 0; ni < 4; ++ni)
                    acc[mi][ni] = __builtin_amdgcn_mfma_f32_16x16x32_bf16(af[mi], bfr[ni], acc[mi][ni], 0, 0, 0);
        }
    }
#pragma unroll
    for (int ni = 0; ni < 4; ++ni) {
        const int col = n0 + wn + ni * 16 + m_l;
        const float bb = bias[col];
#pragma unroll
        for (int mi = 0; mi < 4; ++mi)
#pragma unroll
            for (int r = 0; r < 4; ++r) {
                const int m = m0 + wm + mi * 16 + r0 + r;
                C[(size_t)m * 2048 + col] = (_Float16)(acc[mi][ni][r] + bb);
            }
    }
}

// Persistent recurrent kernel: 32 WGs x 256 thr. WG wg owns hidden units
// [16*wg, 16*wg+16); wave w computes gate w. U B-frags in VGPRs for all 512 steps.
__global__ __launch_bounds__(256) void recur(const _Float16* __restrict__ XW,
                                             const u16* __restrict__ UBF_l,
                                             float* __restrict__ INP,
                                             u16* __restrict__ HBF,
                                             int* __restrict__ cnt,
                                             float* __restrict__ states,
                                             const int layer) {
    __shared__ u16  h_lds[64][264];        // K=256 chunk of h, +8 pad
    __shared__ float z_lds[4][64][17];     // [gate][batch][unit_local], +1 pad
    const int tid = threadIdx.x, lane = tid & 63, wave = tid >> 6;
    const int wg = blockIdx.x;
    const int m_l = lane & 15, k_l = (lane >> 4) * 8, r0 = (lane >> 4) * 4;

    // preload U fragments: col = wave*512 + wg*16 + (lane&15), MFMA B-frag layout
    s16x8 ufrag[16];
    {
        const u16* ub = UBF_l + ((size_t)(wave * 512 + wg * 16 + m_l)) * 512 + k_l;
#pragma unroll
        for (int kf = 0; kf < 16; ++kf) ufrag[kf] = *(const s16x8*)(ub + kf * 32);
    }
    for (int i = tid; i < 64 * 264; i += 256) ((u16*)h_lds)[i] = 0;   // h0 = 0

    const int gb = tid >> 2;           // batch row in gate phase
    const int ug = (tid & 3) * 4;      // unit-local base (4 units per thread)
    const int u  = wg * 16 + ug;       // global unit base
    float cr[4] = {0.f, 0.f, 0.f, 0.f};

    for (int t = 0; t < 512; ++t) {
        f32x4 acc[4] = {};
        if (t > 0) {
            if (tid == 0) {
                while (__hip_atomic_load(&cnt[t - 1], __ATOMIC_ACQUIRE, __HIP_MEMORY_SCOPE_AGENT) < NWG)
                    __builtin_amdgcn_s_sleep(2);
            }
            __syncthreads();
            __threadfence();   // acquire: invalidate stale caches before reading HBF
        }
        const u16* src = HBF + ((t - 1) & 1) * (64 * 512);
#pragma unroll
        for (int half = 0; half < 2; ++half) {
            if (t > 0) {
                __syncthreads();   // previous chunk's MFMA reads done
#pragma unroll
                for (int i = 0; i < 8; ++i) {
                    int e = (tid + i * 256) * 8;           // 16384 bf16 per chunk
                    int b = e >> 8, kl = e & 255;
                    *(s16x8*)&h_lds[b][kl] = *(const s16x8*)(src + (size_t)b * 512 + half * 256 + kl);
                }
            }
            __syncthreads();
#pragma unroll
            for (int kf = 0; kf < 8; ++kf) {
#pragma unroll
                for (int mt = 0; mt < 4; ++mt) {
                    s16x8 af = *(const s16x8*)&h_lds[mt * 16 + m_l][kf * 32 + k_l];
                    acc[mt] = __builtin_amdgcn_mfma_f32_16x16x32_bf16(af, ufrag[half * 8 + kf], acc[mt], 0, 0, 0);
                }
            }
        }
        // z -> LDS (C-layout: col=lane&15 -> unit_local, row -> batch)
#pragma unroll
        for (int mt = 0; mt < 4; ++mt)
#pragma unroll
            for (int r = 0; r < 4; ++r)
                z_lds[wave][mt * 16 + r0 + r][m_l] = acc[mt][r];
        __syncthreads();

        // gate phase: thread handles 4 units of batch row gb
        const _Float16* xwp = XW + ((size_t)t * 64 + gb) * 2048 + u;
        f16x4 xi = *(const f16x4*)(xwp);
        f16x4 xf = *(const f16x4*)(xwp + 512);
        f16x4 xg = *(const f16x4*)(xwp + 1024);
        f16x4 xo = *(const f16x4*)(xwp + 1536);
        float h[4];
#pragma unroll
        for (int j = 0; j < 4; ++j) {
            float zi = (float)xi[j] + z_lds[0][gb][ug + j];
            float zf = (float)xf[j] + z_lds[1][gb][ug + j];
            float zg = (float)xg[j] + z_lds[2][gb][ug + j];
            float zo = (float)xo[j] + z_lds[3][gb][ug + j];
            float cc = sig(zf) * cr[j] + sig(zi) * th(zg);
            cr[j] = cc;
            h[j] = sig(zo) * th(cc);
        }
        u16x4 hb = { f2bf(h[0]), f2bf(h[1]), f2bf(h[2]), f2bf(h[3]) };
        *(u16x4*)&HBF[(t & 1) * (64 * 512) + gb * 512 + u] = hb;
        const size_t oidx = ((size_t)t * 64 + gb) * 512 + u;
        f32x4 hv = { h[0], h[1], h[2], h[3] };
        if (layer) hv += *(const f32x4*)&INP[oidx];
        *(f32x4*)&INP[oidx] = hv;
        if (layer == 0 && t == 511) {
#pragma unroll
            for (int rep = 0; rep < 4; ++rep)
                *(f32x4*)&states[rep * (64 * 512) + gb * 512 + u] = hv;
        }
        __threadfence();       // release h writes
        __syncthreads();
        if (tid == 0)
            __hip_atomic_fetch_add(&cnt[t], 1, __ATOMIC_RELEASE, __HIP_MEMORY_SCOPE_AGENT);
    }
}

// INP[T,B,H] -> out[B,T,H]
__global__ void transpose_out(const float* __restrict__ inp, float* __restrict__ out) {
#pragma unroll
    for (int i = 0; i < 8; ++i) {
        int f = blockIdx.x * 2048 + i * 256 + threadIdx.x;
        int h4 = f & 127, t = (f >> 7) & 511, b = f >> 16;
        f32x4 v = *(const f32x4*)(inp + ((size_t)t * 64 + b) * 512 + h4 * 4);
        *(f32x4*)(out + ((size_t)b * 512 + t) * 512 + h4 * 4) = v;
    }
}

extern "C" void kernel_launch(void* const* d_in, const int* in_sizes, int n_in,
                              void* d_out, int out_size, void* d_ws, size_t ws_size,
                              hipStream_t stream) {
    const float* x = (const float*)d_in[0];
    const float* W = (const float*)d_in[1];
    const float* U = (const float*)d_in[2];
    const float* b = (const float*)d_in[3];
    float* out = (float*)d_out;
    char* ws = (char*)d_ws;

    constexpr size_t INP_OFF = 0;
    constexpr size_t XW_OFF  = 67108864;       // 64 MB
    constexpr size_t WBF_OFF = XW_OFF + 134217728;
    constexpr size_t UBF_OFF = WBF_OFF + 8388608;
    constexpr size_t HBF_OFF = UBF_OFF + 8388608;
    constexpr size_t CNT_OFF = HBF_OFF + 131072;

    float*     INP = (float*)(ws + INP_OFF);
    _Float16*  XW  = (_Float16*)(ws + XW_OFF);
    u16*       WBF = (u16*)(ws + WBF_OFF);
    u16*       UBF = (u16*)(ws + UBF_OFF);
    u16*       HBF = (u16*)(ws + HBF_OFF);
    int*       cnt = (int*)(ws + CNT_OFF);

    init_cnt<<<1, 256, 0, stream>>>(cnt);
    convert_x<<<2048, 256, 0, stream>>>(x, INP);
    convert_wu<<<dim3(64, 16, 8), 256, 0, stream>>>(W, U, WBF, UBF);

    for (int l = 0; l < 4; ++l) {
        gemm_xw<<<dim3(16, 256), 256, 0, stream>>>(INP, WBF + (size_t)l * 1048576,
                                                   b + (size_t)l * 2048, XW);
        recur<<<NWG, 256, 0, stream>>>(XW, UBF + (size_t)l * 1048576, INP, HBF,
                                       cnt + l * 512, out + 16777216, l);
    }
    transpose_out<<<2048, 256, 0, stream>>>(INP, out);
}